// Round 10
// baseline (261.701 us; speedup 1.0000x reference)
//
#include <hip/hip_runtime.h>
#include <stdint.h>

#define N_ROWS 32768
#define K_CODES 1024
#define D_DIM 256
#define NELEM 8388608

// ws layout
#define WS_COUNTS 0               // float[1024]
#define WS_LOSS 1030              // float[1] accumulator: sum z^2 + sum(c*ne^2 - 2*S*ne)
#define WS_ENORM 263168           // float[1024]
#define WS_ROWBEST_BYTES 1056768  // u64[32768]
#define WS_IDX_BYTES 1318912      // u16[32768] = 64KB
#define WS_RTDONE_BYTES 1384448   // int[256] rt completion counters

// out offsets (floats)
#define O_ZQ 0
#define O_LOSS 8388608
#define O_IDX 8388609
#define O_EMB 8421377
#define O_CS 8683521
#define O_EMAW 8684545

// scratch carved out of d_out:
//   Zp: seg-major fp16 [64 segs][32768 rows][16B] = bytes [0, 33554432)
//   Ep: seg-major fp16 [64 segs][1024 rows][16B]  = 1 MB at EP_BYTE_OFF
//   dw: float [256][1024] = 1 MB, reuses bytes [0, 1048576) AFTER k_mm
#define EP_BYTE_OFF 33685520

typedef _Float16 half8 __attribute__((ext_vector_type(8)));
typedef float f32x16 __attribute__((ext_vector_type(16)));

__device__ __forceinline__ unsigned int fenc(float f) {
    unsigned int u = __float_as_uint(f);
    return (u & 0x80000000u) ? ~u : (u | 0x80000000u);
}
__device__ __forceinline__ unsigned long long umin64(unsigned long long a, unsigned long long b) {
    return a < b ? a : b;
}
__device__ __forceinline__ void gll16(const void* g, void* l) {
    __builtin_amdgcn_global_load_lds((const __attribute__((address_space(1))) void*)g,
                                     (__attribute__((address_space(3))) void*)l, 16, 0, 0);
}

// R16: fused conv kernel. gid<2048: conv_z (z_e -> Zp seg-major fp16-split).
// gid>=2048: conv_e (emb -> Ep + enorm) + ws init (counts/loss/rb/rt_done).
// Race-free fusion: the z^2 loss sum MOVED to k_dw (runs after init), so no
// block here both writes and zeroes lossacc.
__global__ __launch_bounds__(256) void k_conv(const float* __restrict__ z_e,
                                              const float* __restrict__ emb,
                                              _Float16* __restrict__ Zp,
                                              _Float16* __restrict__ Ep,
                                              float* __restrict__ enorm,
                                              float* __restrict__ ws) {
    __shared__ float lt[64 * 68];
    __shared__ float red[4];
    int t = threadIdx.x;
    int gid = blockIdx.x;

    if (gid >= 2048) {
        // ---- conv_e + init ----
        int k = gid - 2048, d = t;
        int g2 = k * 256 + d;
        if (g2 < 2048) ws[g2] = 0.0f;   // counts + loss accumulator
        unsigned long long* rb = (unsigned long long*)((char*)ws + WS_ROWBEST_BYTES);
        if (g2 < N_ROWS) rb[g2] = 0xFFFFFFFFFFFFFFFFull;
        int* rtd = (int*)((char*)ws + WS_RTDONE_BYTES);
        if (g2 < 256) rtd[g2] = 0;

        float v = emb[k * 256 + d];
        _Float16 h = (_Float16)v;
        _Float16 l = (_Float16)(v - (float)h);
        int s = d >> 3, sub = d & 7;
        Ep[((size_t)s * 1024 + k) * 8 + sub] = h;
        Ep[((size_t)(32 + s) * 1024 + k) * 8 + sub] = l;
        float sq = v * v;
        #pragma unroll
        for (int off = 32; off >= 1; off >>= 1) sq += __shfl_down(sq, off, 64);
        if ((d & 63) == 0) red[d >> 6] = sq;
        __syncthreads();
        if (d == 0) enorm[k] = (red[0] + red[1]) + (red[2] + red[3]);
        return;
    }

    // ---- conv_z ----
    int hw0 = (gid & 15) * 64, d0 = ((gid >> 4) & 3) * 64, b = gid >> 6;
    const float* src = z_e + (size_t)b * 262144 + (size_t)d0 * 1024 + hw0;
    int dl = t >> 4, hl = (t & 15) * 4;
    #pragma unroll
    for (int i = 0; i < 4; i++) {
        int d = dl + i * 16;
        float4 v = *(const float4*)(src + (size_t)d * 1024 + hl);
        lt[(hl + 0) * 68 + d] = v.x;
        lt[(hl + 1) * 68 + d] = v.y;
        lt[(hl + 2) * 68 + d] = v.z;
        lt[(hl + 3) * 68 + d] = v.w;
    }
    __syncthreads();
    int hr = t >> 2, seg = t & 3;
    int n = b * 1024 + hw0 + hr;
    int sg0 = (d0 >> 3) + seg * 2;   // global hi-seg of first 8 halfs
    half8 hi[2], lo[2];
    #pragma unroll
    for (int p = 0; p < 2; p++) {
        #pragma unroll
        for (int j = 0; j < 8; j++) {
            float v = lt[hr * 68 + seg * 16 + p * 8 + j];
            _Float16 h = (_Float16)v;
            hi[p][j] = h;
            lo[p][j] = (_Float16)(v - (float)h);
        }
    }
    *(half8*)(Zp + ((size_t)(sg0 + 0) * 32768 + n) * 8) = hi[0];
    *(half8*)(Zp + ((size_t)(sg0 + 1) * 32768 + n) * 8) = hi[1];
    *(half8*)(Zp + ((size_t)(32 + sg0) * 32768 + n) * 8) = lo[0];
    *(half8*)(Zp + ((size_t)(33 + sg0) * 32768 + n) * 8) = lo[1];
}

// fused fp16-split GEMM (3-term group fusion) + argmin epilogue + R16 LAST-BLOCK
// FINALIZE: the 8 ct-blocks of each rt share a ws counter; the last to finish
// decodes the 128 row ids (u16 idxs + O_IDX floats) and histograms to counts —
// eliminates the k_fin_idx kernel and its full row_best re-read.
// Correctness is dispatch-order-free: device-scope atomics + threadfence
// release/acquire around the counter; atomicMin-as-read for final values.
// k_mm geometry (R15, measured 61.2us): wave tile 64x64 acc[2][2], 4-wave
// blocks, 128x128 tile, BK=16, LDS 32KB, 4 blocks/CU. CLOSED ARC: schedule
// pokes (R8/R12), BK sweeps (R10), reg-ILP (R12) all <=5%; occupancy (R15) +6%.
__global__ __launch_bounds__(256, 4) void k_mm(const _Float16* __restrict__ Zp,
                                               const _Float16* __restrict__ Ep,
                                               const float* __restrict__ enorm,
                                               unsigned long long* __restrict__ row_best,
                                               unsigned short* __restrict__ idxs,
                                               float* __restrict__ counts,
                                               int* __restrict__ rt_done,
                                               float* __restrict__ out) {
    __shared__ __align__(16) char smem[32768];   // 2 bufs x {zh,zl,eh,el}x4KB; slot+hist reuse
    __shared__ int islast;

    int t = threadIdx.x;
    int lane = t & 63, wv = t >> 6;
    int b = blockIdx.x;
    // bijective XCD swizzle: 2048 blocks, 8 XCDs, 256 contiguous wgids per XCD.
    int wgid = (b & 7) * 256 + (b >> 3);
    int rt = wgid >> 3;        // 0..255: row tile (128 rows)
    int ct = wgid & 7;         // 0..7:   code tile (128 codes)
    int row0 = rt * 128, code0 = ct * 128;

    int wr = wv >> 1, wc = wv & 1;   // 2 x 2 wave grid, wave tile 64x64
    int m31 = lane & 31, ko = lane >> 5;

    f32x16 acc[2][2];
    #pragma unroll
    for (int m = 0; m < 2; m++)
        #pragma unroll
        for (int n = 0; n < 2; n++)
            #pragma unroll
            for (int r = 0; r < 16; r++) acc[m][n][r] = 0.0f;

    // staging split: wave wv stages quadrant wv ({zh,zl,eh,el}), 4 gll16/group
    int quad = wv;
    bool isZ = quad < 2;
    int lobias = (quad & 1) ? 32 : 0;             // quads 1,3 stage the lo segs
    size_t gstride = isZ ? (size_t)32768 * 16 : (size_t)1024 * 16;  // bytes/seg
    const char* gsel = isZ
        ? (const char*)Zp + ((size_t)row0 + lane) * 16
        : (const char*)Ep + ((size_t)code0 + lane) * 16;
    char* lbase = smem + quad * 4096;

    auto STAGE = [&](int g, int buf) {
        #pragma unroll
        for (int s = 0; s < 2; s++) {
            const char* src = gsel + (size_t)(lobias + 2 * g + s) * gstride;
            char* dst = lbase + buf * 16384 + s * 2048;
            gll16(src, dst);
            gll16(src + 64 * 16, dst + 64 * 16);
        }
    };

    STAGE(0, 0);                                  // 4 loads/wave
    STAGE(1, 1);                                  // 4 loads/wave (stay in flight)
    asm volatile("s_waitcnt vmcnt(4)" ::: "memory");   // buf0 landed
    __builtin_amdgcn_s_barrier();
    asm volatile("" ::: "memory");

    for (int g = 0; g < 16; g++) {
        const _Float16* zh = (const _Float16*)(smem + (g & 1) * 16384);
        const _Float16* zl = zh + 2048;
        const _Float16* eh = zh + 4096;
        const _Float16* el = zh + 6144;
        __builtin_amdgcn_s_setprio(1);
        {
            half8 azh[2], azl[2], beh[2], bel[2];
            #pragma unroll
            for (int i = 0; i < 2; i++) {
                azh[i] = *(const half8*)(zh + (ko * 128 + wr * 64 + 32 * i + m31) * 8);
                azl[i] = *(const half8*)(zl + (ko * 128 + wr * 64 + 32 * i + m31) * 8);
                beh[i] = *(const half8*)(eh + (ko * 128 + wc * 64 + 32 * i + m31) * 8);
                bel[i] = *(const half8*)(el + (ko * 128 + wc * 64 + 32 * i + m31) * 8);
            }
            #pragma unroll
            for (int i = 0; i < 2; i++)
                #pragma unroll
                for (int j = 0; j < 2; j++) {
                    acc[i][j] = __builtin_amdgcn_mfma_f32_32x32x16_f16(azh[i], beh[j], acc[i][j], 0, 0, 0);
                    acc[i][j] = __builtin_amdgcn_mfma_f32_32x32x16_f16(azl[i], beh[j], acc[i][j], 0, 0, 0);
                    acc[i][j] = __builtin_amdgcn_mfma_f32_32x32x16_f16(azh[i], bel[j], acc[i][j], 0, 0, 0);
                }
        }
        __builtin_amdgcn_s_setprio(0);
        asm volatile("s_waitcnt lgkmcnt(0)" ::: "memory");  // pin reads above barrier
        __builtin_amdgcn_s_barrier();                       // all waves done reading buf[g&1]
        if (g < 14) STAGE(g + 2, g & 1);                    // refill for group g+2
        if (g < 15) {
            if (g < 14) asm volatile("s_waitcnt vmcnt(4)" ::: "memory");  // buf[g+1] landed
            else        asm volatile("s_waitcnt vmcnt(0)" ::: "memory");  // drain last stage
            __builtin_amdgcn_s_barrier();
            asm volatile("" ::: "memory");
        }
    }

    // epilogue: dist = ||e||^2 - 2*dot
    // C/D 32x32 layout: col=lane&31, row=(reg&3)+8*(reg>>2)+4*(lane>>5)
    unsigned long long* slot = (unsigned long long*)smem;   // [128 rows][32]
    float en0 = enorm[code0 + wc * 64 + m31];
    float en1 = enorm[code0 + wc * 64 + 32 + m31];
    unsigned int col0 = code0 + wc * 64 + m31;
    unsigned int col1 = col0 + 32;

    if (wc == 0) {
        #pragma unroll
        for (int m = 0; m < 2; m++)
            #pragma unroll
            for (int j = 0; j < 16; j++) {
                int row = wr * 64 + m * 32 + 4 * ko + (j & 3) + 8 * (j >> 2);
                unsigned long long p0 = ((unsigned long long)fenc(en0 - 2.0f * acc[m][0][j]) << 32) | col0;
                unsigned long long p1 = ((unsigned long long)fenc(en1 - 2.0f * acc[m][1][j]) << 32) | col1;
                slot[row * 32 + ((m31 + row) & 31)] = umin64(p0, p1);
            }
    }
    __syncthreads();
    if (wc != 0) {
        #pragma unroll
        for (int m = 0; m < 2; m++)
            #pragma unroll
            for (int j = 0; j < 16; j++) {
                int row = wr * 64 + m * 32 + 4 * ko + (j & 3) + 8 * (j >> 2);
                unsigned long long p0 = ((unsigned long long)fenc(en0 - 2.0f * acc[m][0][j]) << 32) | col0;
                unsigned long long p1 = ((unsigned long long)fenc(en1 - 2.0f * acc[m][1][j]) << 32) | col1;
                atomicMin(&slot[row * 32 + ((m31 + row) & 31)], umin64(p0, p1));
            }
    }
    __syncthreads();
    if (t < 128) {
        unsigned long long mm = slot[t * 32 + (t & 31)];
        #pragma unroll
        for (int i = 1; i < 32; i++) mm = umin64(mm, slot[t * 32 + ((i + t) & 31)]);
        atomicMin(&row_best[row0 + t], mm);
    }

    // ---- last-block-per-rt finalize ----
    __syncthreads();                       // all rb atomicMins of this block complete
    if (t == 0) {
        __threadfence();                   // release: our mins ordered before counter bump
        islast = (atomicAdd(&rt_done[rt], 1) == 7);
    }
    __syncthreads();
    if (islast) {
        __threadfence();                   // acquire
        float* hist = (float*)smem;        // 4KB, slot data dead
        #pragma unroll
        for (int j = 0; j < 4; j++) hist[j * 256 + t] = 0.0f;
        __syncthreads();
        if (t < 128) {
            unsigned long long v = atomicMin(&row_best[row0 + t], 0xFFFFFFFFFFFFFFFFull); // atomic read
            int id = (int)(v & 0xFFFFFFFFull);
            idxs[row0 + t] = (unsigned short)id;
            out[O_IDX + row0 + t] = (float)id;
            atomicAdd(&hist[id], 1.0f);
        }
        __syncthreads();
        #pragma unroll
        for (int j = 0; j < 4; j++) {
            float h = hist[j * 256 + t];
            if (h != 0.0f) atomicAdd(&counts[j * 256 + t], h);
        }
    }
}

// dw segment-sum: one block per d (256 blocks x 512 thr), ALL 32 batches in
// LDS; 2-replica histogram (replica = t&1); merge on flush. R16: also computes
// the z^2 loss sum (each z_e element read exactly once here) — moved from
// conv_z so the fused k_conv has no init/accumulate race. u16 idxs (16MB read).
__global__ __launch_bounds__(512) void k_dw(const float* __restrict__ z_e,
                                            const unsigned short* __restrict__ idxs,
                                            float* __restrict__ dw,
                                            float* __restrict__ lossacc) {
    __shared__ float acc[2 * K_CODES];
    __shared__ float red8[8];
    int t = threadIdx.x;
    int d = blockIdx.x;   // 0..255
    #pragma unroll
    for (int j = 0; j < 4; j++) acc[j * 512 + t] = 0.0f;
    __syncthreads();
    int rep = (t & 1) * K_CODES;
    float sq = 0.0f;
    for (int b = 0; b < 32; b++) {
        ushort2 id2 = *(const ushort2*)(idxs + b * 1024 + t * 2);
        float2 v = *(const float2*)(z_e + (size_t)b * 262144 + (size_t)d * 1024 + t * 2);
        sq += v.x * v.x + v.y * v.y;
        atomicAdd(&acc[rep + id2.x], v.x);
        atomicAdd(&acc[rep + id2.y], v.y);
    }
    __syncthreads();
    float* pr = dw + (size_t)d * 1024;
    #pragma unroll
    for (int j = 0; j < 2; j++) pr[j * 512 + t] = acc[j * 512 + t] + acc[K_CODES + j * 512 + t];
    // z^2 block reduction, one atomic per block
    #pragma unroll
    for (int off = 32; off >= 1; off >>= 1) sq += __shfl_down(sq, off, 64);
    if ((t & 63) == 0) red8[t >> 6] = sq;
    __syncthreads();
    if (t == 0) {
        float s = 0.0f;
        #pragma unroll
        for (int j = 0; j < 8; j++) s += red8[j];
        atomicAdd(lossacc, s);
    }
}

// EMA finalize + loss code-terms from dw[d][k] (1 MB). block = 64-code x 64-d tile.
// loss terms: sum over (k,d): craw[k]*ne^2 - 2*S*ne  (S = raw segment sum)
__global__ __launch_bounds__(256) void k_red(const float* __restrict__ dw,
                                             const float* __restrict__ ema_cs,
                                             const float* __restrict__ ema_w,
                                             const float* __restrict__ counts,
                                             float* __restrict__ lossacc,
                                             float* __restrict__ out) {
    __shared__ float tile[64 * 69];   // [d][k] raw sums, pad 69
    __shared__ float csl[64];
    __shared__ float craw[64];
    __shared__ float red[4];
    int t = threadIdx.x;
    int k0 = blockIdx.x * 64, d0 = blockIdx.y * 64;
    int dr = t >> 4, kc = t & 15;
    if (t < 64) {
        float c = counts[k0 + t];
        craw[t] = c;
        csl[t] = 0.99f * ema_cs[k0 + t] + 0.01f * c;
    }
    #pragma unroll
    for (int q = 0; q < 4; q++) {
        float4 v = *(const float4*)(dw + (size_t)(d0 + dr + 16 * q) * 1024 + k0 + kc * 4);
        float* p = tile + (dr + 16 * q) * 69 + kc * 4;
        p[0] = v.x; p[1] = v.y; p[2] = v.z; p[3] = v.w;
    }
    __syncthreads();
    int kk = t >> 2, dq = t & 3;
    int k = k0 + kk;
    float inv = 1.0f / (csl[kk] + 1e-5f);
    float cr = craw[kk];
    float lterm = 0.0f;
    #pragma unroll
    for (int j4 = 0; j4 < 4; j4++) {
        int dd = dq * 16 + j4 * 4;
        size_t kd = (size_t)k * 256 + d0 + dd;
        float4 w = *(const float4*)(ema_w + kd);
        float s0 = tile[(dd + 0) * 69 + kk];
        float s1 = tile[(dd + 1) * 69 + kk];
        float s2 = tile[(dd + 2) * 69 + kk];
        float s3 = tile[(dd + 3) * 69 + kk];
        float4 nw;
        nw.x = 0.99f * w.x + 0.01f * s0;
        nw.y = 0.99f * w.y + 0.01f * s1;
        nw.z = 0.99f * w.z + 0.01f * s2;
        nw.w = 0.99f * w.w + 0.01f * s3;
        *(float4*)(out + O_EMAW + kd) = nw;
        float4 ne = {nw.x * inv, nw.y * inv, nw.z * inv, nw.w * inv};
        *(float4*)(out + O_EMB + kd) = ne;
        lterm += ne.x * (cr * ne.x - 2.0f * s0);
        lterm += ne.y * (cr * ne.y - 2.0f * s1);
        lterm += ne.z * (cr * ne.z - 2.0f * s2);
        lterm += ne.w * (cr * ne.w - 2.0f * s3);
    }
    if (blockIdx.y == 0 && t < 64) out[O_CS + k0 + t] = csl[t];
    // block-reduce loss term, one atomic per block
    #pragma unroll
    for (int off = 32; off >= 1; off >>= 1) lterm += __shfl_down(lterm, off, 64);
    if ((t & 63) == 0) red[t >> 6] = lterm;
    __syncthreads();
    if (t == 0) atomicAdd(lossacc, (red[0] + red[1]) + (red[2] + red[3]));
}

// broadcast z_q_st = new_embedding[idx]; u16 idxs. block = 64 hw x 64 d;
// gather coalesced float4 (4 lanes/row), write coalesced over hw via LDS
// transpose. Also writes the final loss.
__global__ __launch_bounds__(256) void k_bcast(const unsigned short* __restrict__ idxs,
                                               const float* __restrict__ lossacc,
                                               float* __restrict__ out) {
    __shared__ float lt[64 * 68];
    __shared__ int sid[64];
    int t = threadIdx.x;
    int hw0 = blockIdx.x * 64, d0 = blockIdx.y * 64, b = blockIdx.z;
    if (t < 64) sid[t] = idxs[b * 1024 + hw0 + t];
    __syncthreads();
    int r = t >> 2, c = t & 3;
    const float* nrow = out + O_EMB + (size_t)sid[r] * 256 + d0;
    #pragma unroll
    for (int it = 0; it < 4; it++) {
        int dd = it * 16 + c * 4;
        float4 q = *(const float4*)(nrow + dd);
        float* p = lt + r * 68 + dd;
        p[0] = q.x; p[1] = q.y; p[2] = q.z; p[3] = q.w;
    }
    __syncthreads();
    int dl = t >> 4, hl = (t & 15) * 4;
    float* dst = out + O_ZQ + (size_t)b * 262144 + (size_t)d0 * 1024 + hw0;
    #pragma unroll
    for (int i = 0; i < 4; i++) {
        int d = dl + i * 16;
        float4 w;
        w.x = lt[(hl + 0) * 68 + d];
        w.y = lt[(hl + 1) * 68 + d];
        w.z = lt[(hl + 2) * 68 + d];
        w.w = lt[(hl + 3) * 68 + d];
        *(float4*)(dst + (size_t)d * 1024 + hl) = w;
    }
    if (blockIdx.x == 0 && blockIdx.y == 0 && blockIdx.z == 0 && t == 0)
        out[O_LOSS] = lossacc[0] * 2.9802322387695312e-08f;   // * BETA / NELEM
}

extern "C" void kernel_launch(void* const* d_in, const int* in_sizes, int n_in,
                              void* d_out, int out_size, void* d_ws, size_t ws_size,
                              hipStream_t stream) {
    const float* z_e = (const float*)d_in[0];
    const float* emb = (const float*)d_in[1];
    const float* ema_cs = (const float*)d_in[2];
    const float* ema_w = (const float*)d_in[3];
    float* out = (float*)d_out;
    float* ws = (float*)d_ws;

    float* counts = ws + WS_COUNTS;
    float* lossacc = ws + WS_LOSS;
    float* enorm = ws + WS_ENORM;
    unsigned long long* row_best = (unsigned long long*)((char*)d_ws + WS_ROWBEST_BYTES);
    unsigned short* idxs = (unsigned short*)((char*)d_ws + WS_IDX_BYTES);
    int* rt_done = (int*)((char*)d_ws + WS_RTDONE_BYTES);

    _Float16* Zp = (_Float16*)d_out;                        // dead after k_mm
    _Float16* Ep = (_Float16*)((char*)d_out + EP_BYTE_OFF); // dead after k_red
    float* dw = (float*)d_out;                              // 1 MB, reuses Zp region after k_mm

    k_conv<<<3072, 256, 0, stream>>>(z_e, emb, Zp, Ep, enorm, ws);   // conv_z + conv_e + init
    k_mm<<<2048, 256, 0, stream>>>(Zp, Ep, enorm, row_best, idxs, counts, rt_done, out);
    k_dw<<<256, 512, 0, stream>>>(z_e, idxs, dw, lossacc);
    k_red<<<dim3(16, 4), 256, 0, stream>>>(dw, ema_cs, ema_w, counts, lossacc, out);
    k_bcast<<<dim3(16, 4, 32), 256, 0, stream>>>(idxs, lossacc, out);
}

// Round 11
// 215.065 us; speedup vs baseline: 1.2168x; 1.2168x over previous
//
#include <hip/hip_runtime.h>
#include <stdint.h>

#define N_ROWS 32768
#define K_CODES 1024
#define D_DIM 256
#define NELEM 8388608

// ws layout
#define WS_COUNTS 0               // float[1024]
#define WS_LOSS 1030              // float[1] accumulator: sum z^2 + sum(c*ne^2 - 2*S*ne)
#define WS_ENORM 263168           // float[1024]
#define WS_ROWBEST_BYTES 1056768  // u64[32768]
#define WS_IDX_BYTES 1318912      // u16[32768] = 64KB

// out offsets (floats)
#define O_ZQ 0
#define O_LOSS 8388608
#define O_IDX 8388609
#define O_EMB 8421377
#define O_CS 8683521
#define O_EMAW 8684545

// scratch carved out of d_out:
//   Zp: seg-major fp16 [64 segs][32768 rows][16B] = bytes [0, 33554432)
//   Ep: seg-major fp16 [64 segs][1024 rows][16B]  = 1 MB at EP_BYTE_OFF
//   dw: float [256][1024] = 1 MB, reuses bytes [0, 1048576) AFTER k_mm
#define EP_BYTE_OFF 33685520

typedef _Float16 half8 __attribute__((ext_vector_type(8)));
typedef float f32x16 __attribute__((ext_vector_type(16)));

__device__ __forceinline__ unsigned int fenc(float f) {
    unsigned int u = __float_as_uint(f);
    return (u & 0x80000000u) ? ~u : (u | 0x80000000u);
}
__device__ __forceinline__ unsigned long long umin64(unsigned long long a, unsigned long long b) {
    return a < b ? a : b;
}
__device__ __forceinline__ void gll16(const void* g, void* l) {
    __builtin_amdgcn_global_load_lds((const __attribute__((address_space(1))) void*)g,
                                     (__attribute__((address_space(3))) void*)l, 16, 0, 0);
}

// Fused conv kernel (R16, kept — part of the measured ~25us non-mm saving).
// gid<2048: conv_z (z_e -> Zp seg-major fp16-split).
// gid>=2048: conv_e (emb -> Ep + enorm) + ws init (counts/loss/rb).
// Race-free: the z^2 loss sum lives in k_dw (runs after init).
__global__ __launch_bounds__(256) void k_conv(const float* __restrict__ z_e,
                                              const float* __restrict__ emb,
                                              _Float16* __restrict__ Zp,
                                              _Float16* __restrict__ Ep,
                                              float* __restrict__ enorm,
                                              float* __restrict__ ws) {
    __shared__ float lt[64 * 68];
    __shared__ float red[4];
    int t = threadIdx.x;
    int gid = blockIdx.x;

    if (gid >= 2048) {
        // ---- conv_e + init ----
        int k = gid - 2048, d = t;
        int g2 = k * 256 + d;
        if (g2 < 2048) ws[g2] = 0.0f;   // counts + loss accumulator
        unsigned long long* rb = (unsigned long long*)((char*)ws + WS_ROWBEST_BYTES);
        if (g2 < N_ROWS) rb[g2] = 0xFFFFFFFFFFFFFFFFull;

        float v = emb[k * 256 + d];
        _Float16 h = (_Float16)v;
        _Float16 l = (_Float16)(v - (float)h);
        int s = d >> 3, sub = d & 7;
        Ep[((size_t)s * 1024 + k) * 8 + sub] = h;
        Ep[((size_t)(32 + s) * 1024 + k) * 8 + sub] = l;
        float sq = v * v;
        #pragma unroll
        for (int off = 32; off >= 1; off >>= 1) sq += __shfl_down(sq, off, 64);
        if ((d & 63) == 0) red[d >> 6] = sq;
        __syncthreads();
        if (d == 0) enorm[k] = (red[0] + red[1]) + (red[2] + red[3]);
        return;
    }

    // ---- conv_z ----
    int hw0 = (gid & 15) * 64, d0 = ((gid >> 4) & 3) * 64, b = gid >> 6;
    const float* src = z_e + (size_t)b * 262144 + (size_t)d0 * 1024 + hw0;
    int dl = t >> 4, hl = (t & 15) * 4;
    #pragma unroll
    for (int i = 0; i < 4; i++) {
        int d = dl + i * 16;
        float4 v = *(const float4*)(src + (size_t)d * 1024 + hl);
        lt[(hl + 0) * 68 + d] = v.x;
        lt[(hl + 1) * 68 + d] = v.y;
        lt[(hl + 2) * 68 + d] = v.z;
        lt[(hl + 3) * 68 + d] = v.w;
    }
    __syncthreads();
    int hr = t >> 2, seg = t & 3;
    int n = b * 1024 + hw0 + hr;
    int sg0 = (d0 >> 3) + seg * 2;   // global hi-seg of first 8 halfs
    half8 hi[2], lo[2];
    #pragma unroll
    for (int p = 0; p < 2; p++) {
        #pragma unroll
        for (int j = 0; j < 8; j++) {
            float v = lt[hr * 68 + seg * 16 + p * 8 + j];
            _Float16 h = (_Float16)v;
            hi[p][j] = h;
            lo[p][j] = (_Float16)(v - (float)h);
        }
    }
    *(half8*)(Zp + ((size_t)(sg0 + 0) * 32768 + n) * 8) = hi[0];
    *(half8*)(Zp + ((size_t)(sg0 + 1) * 32768 + n) * 8) = hi[1];
    *(half8*)(Zp + ((size_t)(32 + sg0) * 32768 + n) * 8) = lo[0];
    *(half8*)(Zp + ((size_t)(33 + sg0) * 32768 + n) * 8) = lo[1];
}

// fused fp16-split GEMM (3-term group fusion) + argmin epilogue.
// R17 = R15 EXACT (measured 61.2us, MfmaUtil 37%, 4 blocks/CU). R16's in-kernel
// last-block finalize REMOVED: its per-block device-scope __threadfence
// serialized all 2048 block tails (61->115us, MfmaUtil 18%). Finalize is a
// separate tiny kernel again. CLOSED ARC: schedule pokes (R8/R12), BK sweeps
// (R10), reg-ILP (R12) all <=5%; occupancy doubling (R15) +6%; in-GEMM
// cross-block epilogue (R16) -88%.
__global__ __launch_bounds__(256, 4) void k_mm(const _Float16* __restrict__ Zp,
                                               const _Float16* __restrict__ Ep,
                                               const float* __restrict__ enorm,
                                               unsigned long long* __restrict__ row_best) {
    __shared__ __align__(16) char smem[32768];   // 2 bufs x {zh,zl,eh,el}x4KB; slot reuses all

    int t = threadIdx.x;
    int lane = t & 63, wv = t >> 6;
    int b = blockIdx.x;
    // bijective XCD swizzle: 2048 blocks, 8 XCDs, 256 contiguous wgids per XCD.
    int wgid = (b & 7) * 256 + (b >> 3);
    int rt = wgid >> 3;        // 0..255: row tile (128 rows)
    int ct = wgid & 7;         // 0..7:   code tile (128 codes)
    int row0 = rt * 128, code0 = ct * 128;

    int wr = wv >> 1, wc = wv & 1;   // 2 x 2 wave grid, wave tile 64x64
    int m31 = lane & 31, ko = lane >> 5;

    f32x16 acc[2][2];
    #pragma unroll
    for (int m = 0; m < 2; m++)
        #pragma unroll
        for (int n = 0; n < 2; n++)
            #pragma unroll
            for (int r = 0; r < 16; r++) acc[m][n][r] = 0.0f;

    // staging split: wave wv stages quadrant wv ({zh,zl,eh,el}), 4 gll16/group
    int quad = wv;
    bool isZ = quad < 2;
    int lobias = (quad & 1) ? 32 : 0;             // quads 1,3 stage the lo segs
    size_t gstride = isZ ? (size_t)32768 * 16 : (size_t)1024 * 16;  // bytes/seg
    const char* gsel = isZ
        ? (const char*)Zp + ((size_t)row0 + lane) * 16
        : (const char*)Ep + ((size_t)code0 + lane) * 16;
    char* lbase = smem + quad * 4096;

    auto STAGE = [&](int g, int buf) {
        #pragma unroll
        for (int s = 0; s < 2; s++) {
            const char* src = gsel + (size_t)(lobias + 2 * g + s) * gstride;
            char* dst = lbase + buf * 16384 + s * 2048;
            gll16(src, dst);
            gll16(src + 64 * 16, dst + 64 * 16);
        }
    };

    STAGE(0, 0);                                  // 4 loads/wave
    STAGE(1, 1);                                  // 4 loads/wave (stay in flight)
    asm volatile("s_waitcnt vmcnt(4)" ::: "memory");   // buf0 landed
    __builtin_amdgcn_s_barrier();
    asm volatile("" ::: "memory");

    for (int g = 0; g < 16; g++) {
        const _Float16* zh = (const _Float16*)(smem + (g & 1) * 16384);
        const _Float16* zl = zh + 2048;
        const _Float16* eh = zh + 4096;
        const _Float16* el = zh + 6144;
        __builtin_amdgcn_s_setprio(1);
        {
            half8 azh[2], azl[2], beh[2], bel[2];
            #pragma unroll
            for (int i = 0; i < 2; i++) {
                azh[i] = *(const half8*)(zh + (ko * 128 + wr * 64 + 32 * i + m31) * 8);
                azl[i] = *(const half8*)(zl + (ko * 128 + wr * 64 + 32 * i + m31) * 8);
                beh[i] = *(const half8*)(eh + (ko * 128 + wc * 64 + 32 * i + m31) * 8);
                bel[i] = *(const half8*)(el + (ko * 128 + wc * 64 + 32 * i + m31) * 8);
            }
            #pragma unroll
            for (int i = 0; i < 2; i++)
                #pragma unroll
                for (int j = 0; j < 2; j++) {
                    acc[i][j] = __builtin_amdgcn_mfma_f32_32x32x16_f16(azh[i], beh[j], acc[i][j], 0, 0, 0);
                    acc[i][j] = __builtin_amdgcn_mfma_f32_32x32x16_f16(azl[i], beh[j], acc[i][j], 0, 0, 0);
                    acc[i][j] = __builtin_amdgcn_mfma_f32_32x32x16_f16(azh[i], bel[j], acc[i][j], 0, 0, 0);
                }
        }
        __builtin_amdgcn_s_setprio(0);
        asm volatile("s_waitcnt lgkmcnt(0)" ::: "memory");  // pin reads above barrier
        __builtin_amdgcn_s_barrier();                       // all waves done reading buf[g&1]
        if (g < 14) STAGE(g + 2, g & 1);                    // refill for group g+2
        if (g < 15) {
            if (g < 14) asm volatile("s_waitcnt vmcnt(4)" ::: "memory");  // buf[g+1] landed
            else        asm volatile("s_waitcnt vmcnt(0)" ::: "memory");  // drain last stage
            __builtin_amdgcn_s_barrier();
            asm volatile("" ::: "memory");
        }
    }

    // epilogue: dist = ||e||^2 - 2*dot
    // C/D 32x32 layout: col=lane&31, row=(reg&3)+8*(reg>>2)+4*(lane>>5)
    unsigned long long* slot = (unsigned long long*)smem;   // [128 rows][32]
    float en0 = enorm[code0 + wc * 64 + m31];
    float en1 = enorm[code0 + wc * 64 + 32 + m31];
    unsigned int col0 = code0 + wc * 64 + m31;
    unsigned int col1 = col0 + 32;

    if (wc == 0) {
        #pragma unroll
        for (int m = 0; m < 2; m++)
            #pragma unroll
            for (int j = 0; j < 16; j++) {
                int row = wr * 64 + m * 32 + 4 * ko + (j & 3) + 8 * (j >> 2);
                unsigned long long p0 = ((unsigned long long)fenc(en0 - 2.0f * acc[m][0][j]) << 32) | col0;
                unsigned long long p1 = ((unsigned long long)fenc(en1 - 2.0f * acc[m][1][j]) << 32) | col1;
                slot[row * 32 + ((m31 + row) & 31)] = umin64(p0, p1);
            }
    }
    __syncthreads();
    if (wc != 0) {
        #pragma unroll
        for (int m = 0; m < 2; m++)
            #pragma unroll
            for (int j = 0; j < 16; j++) {
                int row = wr * 64 + m * 32 + 4 * ko + (j & 3) + 8 * (j >> 2);
                unsigned long long p0 = ((unsigned long long)fenc(en0 - 2.0f * acc[m][0][j]) << 32) | col0;
                unsigned long long p1 = ((unsigned long long)fenc(en1 - 2.0f * acc[m][1][j]) << 32) | col1;
                atomicMin(&slot[row * 32 + ((m31 + row) & 31)], umin64(p0, p1));
            }
    }
    __syncthreads();
    if (t < 128) {
        unsigned long long mm = slot[t * 32 + (t & 31)];
        #pragma unroll
        for (int i = 1; i < 32; i++) mm = umin64(mm, slot[t * 32 + ((i + t) & 31)]);
        atomicMin(&row_best[row0 + t], mm);
    }
}

// finalize indices (u16 + O_IDX floats) + histogram (counts) in one pass
__global__ __launch_bounds__(256) void k_fin_idx(const unsigned long long* __restrict__ rb,
                                                 unsigned short* __restrict__ idxs,
                                                 float* __restrict__ counts,
                                                 float* __restrict__ out) {
    __shared__ float hist[K_CODES];
    int t = threadIdx.x;
    #pragma unroll
    for (int j = 0; j < 4; j++) hist[j * 256 + t] = 0.0f;
    __syncthreads();
    int i = blockIdx.x * 256 + t;
    int id = (int)(rb[i] & 0xFFFFFFFFull);
    idxs[i] = (unsigned short)id;
    out[O_IDX + i] = (float)id;
    atomicAdd(&hist[id], 1.0f);
    __syncthreads();
    #pragma unroll
    for (int j = 0; j < 4; j++) {
        float h = hist[j * 256 + t];
        if (h != 0.0f) atomicAdd(&counts[j * 256 + t], h);
    }
}

// dw segment-sum: one block per d (256 blocks x 512 thr), ALL 32 batches in
// LDS; 2-replica histogram (replica = t&1); merge on flush. Also computes the
// z^2 loss sum (each z_e element read exactly once here). u16 idxs (16MB read).
__global__ __launch_bounds__(512) void k_dw(const float* __restrict__ z_e,
                                            const unsigned short* __restrict__ idxs,
                                            float* __restrict__ dw,
                                            float* __restrict__ lossacc) {
    __shared__ float acc[2 * K_CODES];
    __shared__ float red8[8];
    int t = threadIdx.x;
    int d = blockIdx.x;   // 0..255
    #pragma unroll
    for (int j = 0; j < 4; j++) acc[j * 512 + t] = 0.0f;
    __syncthreads();
    int rep = (t & 1) * K_CODES;
    float sq = 0.0f;
    for (int b = 0; b < 32; b++) {
        ushort2 id2 = *(const ushort2*)(idxs + b * 1024 + t * 2);
        float2 v = *(const float2*)(z_e + (size_t)b * 262144 + (size_t)d * 1024 + t * 2);
        sq += v.x * v.x + v.y * v.y;
        atomicAdd(&acc[rep + id2.x], v.x);
        atomicAdd(&acc[rep + id2.y], v.y);
    }
    __syncthreads();
    float* pr = dw + (size_t)d * 1024;
    #pragma unroll
    for (int j = 0; j < 2; j++) pr[j * 512 + t] = acc[j * 512 + t] + acc[K_CODES + j * 512 + t];
    // z^2 block reduction, one atomic per block
    #pragma unroll
    for (int off = 32; off >= 1; off >>= 1) sq += __shfl_down(sq, off, 64);
    if ((t & 63) == 0) red8[t >> 6] = sq;
    __syncthreads();
    if (t == 0) {
        float s = 0.0f;
        #pragma unroll
        for (int j = 0; j < 8; j++) s += red8[j];
        atomicAdd(lossacc, s);
    }
}

// EMA finalize + loss code-terms from dw[d][k] (1 MB). block = 64-code x 64-d tile.
// loss terms: sum over (k,d): craw[k]*ne^2 - 2*S*ne  (S = raw segment sum)
__global__ __launch_bounds__(256) void k_red(const float* __restrict__ dw,
                                             const float* __restrict__ ema_cs,
                                             const float* __restrict__ ema_w,
                                             const float* __restrict__ counts,
                                             float* __restrict__ lossacc,
                                             float* __restrict__ out) {
    __shared__ float tile[64 * 69];   // [d][k] raw sums, pad 69
    __shared__ float csl[64];
    __shared__ float craw[64];
    __shared__ float red[4];
    int t = threadIdx.x;
    int k0 = blockIdx.x * 64, d0 = blockIdx.y * 64;
    int dr = t >> 4, kc = t & 15;
    if (t < 64) {
        float c = counts[k0 + t];
        craw[t] = c;
        csl[t] = 0.99f * ema_cs[k0 + t] + 0.01f * c;
    }
    #pragma unroll
    for (int q = 0; q < 4; q++) {
        float4 v = *(const float4*)(dw + (size_t)(d0 + dr + 16 * q) * 1024 + k0 + kc * 4);
        float* p = tile + (dr + 16 * q) * 69 + kc * 4;
        p[0] = v.x; p[1] = v.y; p[2] = v.z; p[3] = v.w;
    }
    __syncthreads();
    int kk = t >> 2, dq = t & 3;
    int k = k0 + kk;
    float inv = 1.0f / (csl[kk] + 1e-5f);
    float cr = craw[kk];
    float lterm = 0.0f;
    #pragma unroll
    for (int j4 = 0; j4 < 4; j4++) {
        int dd = dq * 16 + j4 * 4;
        size_t kd = (size_t)k * 256 + d0 + dd;
        float4 w = *(const float4*)(ema_w + kd);
        float s0 = tile[(dd + 0) * 69 + kk];
        float s1 = tile[(dd + 1) * 69 + kk];
        float s2 = tile[(dd + 2) * 69 + kk];
        float s3 = tile[(dd + 3) * 69 + kk];
        float4 nw;
        nw.x = 0.99f * w.x + 0.01f * s0;
        nw.y = 0.99f * w.y + 0.01f * s1;
        nw.z = 0.99f * w.z + 0.01f * s2;
        nw.w = 0.99f * w.w + 0.01f * s3;
        *(float4*)(out + O_EMAW + kd) = nw;
        float4 ne = {nw.x * inv, nw.y * inv, nw.z * inv, nw.w * inv};
        *(float4*)(out + O_EMB + kd) = ne;
        lterm += ne.x * (cr * ne.x - 2.0f * s0);
        lterm += ne.y * (cr * ne.y - 2.0f * s1);
        lterm += ne.z * (cr * ne.z - 2.0f * s2);
        lterm += ne.w * (cr * ne.w - 2.0f * s3);
    }
    if (blockIdx.y == 0 && t < 64) out[O_CS + k0 + t] = csl[t];
    // block-reduce loss term, one atomic per block
    #pragma unroll
    for (int off = 32; off >= 1; off >>= 1) lterm += __shfl_down(lterm, off, 64);
    if ((t & 63) == 0) red[t >> 6] = lterm;
    __syncthreads();
    if (t == 0) atomicAdd(lossacc, (red[0] + red[1]) + (red[2] + red[3]));
}

// broadcast z_q_st = new_embedding[idx]; u16 idxs. block = 64 hw x 64 d;
// gather coalesced float4 (4 lanes/row), write coalesced over hw via LDS
// transpose. Also writes the final loss.
__global__ __launch_bounds__(256) void k_bcast(const unsigned short* __restrict__ idxs,
                                               const float* __restrict__ lossacc,
                                               float* __restrict__ out) {
    __shared__ float lt[64 * 68];
    __shared__ int sid[64];
    int t = threadIdx.x;
    int hw0 = blockIdx.x * 64, d0 = blockIdx.y * 64, b = blockIdx.z;
    if (t < 64) sid[t] = idxs[b * 1024 + hw0 + t];
    __syncthreads();
    int r = t >> 2, c = t & 3;
    const float* nrow = out + O_EMB + (size_t)sid[r] * 256 + d0;
    #pragma unroll
    for (int it = 0; it < 4; it++) {
        int dd = it * 16 + c * 4;
        float4 q = *(const float4*)(nrow + dd);
        float* p = lt + r * 68 + dd;
        p[0] = q.x; p[1] = q.y; p[2] = q.z; p[3] = q.w;
    }
    __syncthreads();
    int dl = t >> 4, hl = (t & 15) * 4;
    float* dst = out + O_ZQ + (size_t)b * 262144 + (size_t)d0 * 1024 + hw0;
    #pragma unroll
    for (int i = 0; i < 4; i++) {
        int d = dl + i * 16;
        float4 w;
        w.x = lt[(hl + 0) * 68 + d];
        w.y = lt[(hl + 1) * 68 + d];
        w.z = lt[(hl + 2) * 68 + d];
        w.w = lt[(hl + 3) * 68 + d];
        *(float4*)(dst + (size_t)d * 1024 + hl) = w;
    }
    if (blockIdx.x == 0 && blockIdx.y == 0 && blockIdx.z == 0 && t == 0)
        out[O_LOSS] = lossacc[0] * 2.9802322387695312e-08f;   // * BETA / NELEM
}

extern "C" void kernel_launch(void* const* d_in, const int* in_sizes, int n_in,
                              void* d_out, int out_size, void* d_ws, size_t ws_size,
                              hipStream_t stream) {
    const float* z_e = (const float*)d_in[0];
    const float* emb = (const float*)d_in[1];
    const float* ema_cs = (const float*)d_in[2];
    const float* ema_w = (const float*)d_in[3];
    float* out = (float*)d_out;
    float* ws = (float*)d_ws;

    float* counts = ws + WS_COUNTS;
    float* lossacc = ws + WS_LOSS;
    float* enorm = ws + WS_ENORM;
    unsigned long long* row_best = (unsigned long long*)((char*)d_ws + WS_ROWBEST_BYTES);
    unsigned short* idxs = (unsigned short*)((char*)d_ws + WS_IDX_BYTES);

    _Float16* Zp = (_Float16*)d_out;                        // dead after k_mm
    _Float16* Ep = (_Float16*)((char*)d_out + EP_BYTE_OFF); // dead after k_red
    float* dw = (float*)d_out;                              // 1 MB, reuses Zp region after k_mm

    k_conv<<<3072, 256, 0, stream>>>(z_e, emb, Zp, Ep, enorm, ws);   // conv_z + conv_e + init
    k_mm<<<2048, 256, 0, stream>>>(Zp, Ep, enorm, row_best);
    k_fin_idx<<<128, 256, 0, stream>>>(row_best, idxs, counts, out);
    k_dw<<<256, 512, 0, stream>>>(z_e, idxs, dw, lossacc);
    k_red<<<dim3(16, 4), 256, 0, stream>>>(dw, ema_cs, ema_w, counts, lossacc, out);
    k_bcast<<<dim3(16, 4, 32), 256, 0, stream>>>(idxs, lossacc, out);
}